// Round 11
// baseline (182.986 us; speedup 1.0000x reference)
//
#include <hip/hip_runtime.h>
#include <stdint.h>

#define Mdim 4096
#define Kdim 4096
#define Ndim 4096

typedef __attribute__((ext_vector_type(8))) short bf16x8;   // 8 bf16 (MFMA A/B frag)
typedef __attribute__((ext_vector_type(4))) float f32x4;    // 16x16 MFMA C/D frag

static __device__ __forceinline__ unsigned short f2bf_rne(float f) {
    union { float f; unsigned u; } v; v.f = f;
    unsigned u = v.u;
    u += 0x7FFFu + ((u >> 16) & 1u);
    return (unsigned short)(u >> 16);
}

static __device__ __forceinline__ void gload_lds16(const unsigned short* g, unsigned short* l) {
    __builtin_amdgcn_global_load_lds(
        (const __attribute__((address_space(1))) unsigned int*)g,
        (__attribute__((address_space(3))) unsigned int*)l,
        16, 0, 0);
}

#define BAR()   do { asm volatile("" ::: "memory"); __builtin_amdgcn_s_barrier(); asm volatile("" ::: "memory"); } while (0)
#define VMC(N)  asm volatile("s_waitcnt vmcnt(" #N ")" ::: "memory")
#define SB()    __builtin_amdgcn_sched_barrier(0)

// ---------------------------------------------------------------------------
// Packing kernels: f32 -> bf16, k-major 16B-unit layout (unchanged from r9).
// A_p[(kt*8+o)*4096 + row] = A[row][kt*64+o*8 .. +8]
// B_p[(kt*8+o)*4096 + col] = B[kt*64+o*8 .. +8][col]   (B^T, k-major)
// ---------------------------------------------------------------------------
__global__ void conv_a_pack(const float* __restrict__ a, unsigned short* __restrict__ out) {
    __shared__ float tile[64][65];
    const int kt = blockIdx.x, rt = blockIdx.y;
    for (int i = threadIdx.x; i < 64 * 64; i += 256) {
        int r = i >> 6, c = i & 63;
        tile[r][c] = a[(size_t)(rt * 64 + r) * Kdim + kt * 64 + c];
    }
    __syncthreads();
    for (int i = threadIdx.x; i < 512; i += 256) {
        int o = i >> 6, r = i & 63;
        bf16x8 v;
#pragma unroll
        for (int e = 0; e < 8; ++e) v[e] = (short)f2bf_rne(tile[r][o * 8 + e]);
        ((bf16x8*)out)[(size_t)(kt * 8 + o) * 4096 + rt * 64 + r] = v;
    }
}

__global__ void conv_b_pack(const float* __restrict__ b, unsigned short* __restrict__ out) {
    __shared__ float tile[64][65];
    const int kt = blockIdx.x, nt = blockIdx.y;
    for (int i = threadIdx.x; i < 64 * 64; i += 256) {
        int kk = i >> 6, n = i & 63;
        tile[kk][n] = b[(size_t)(kt * 64 + kk) * Ndim + nt * 64 + n];
    }
    __syncthreads();
    for (int i = threadIdx.x; i < 512; i += 256) {
        int o = i >> 6, n = i & 63;
        bf16x8 v;
#pragma unroll
        for (int e = 0; e < 8; ++e) v[e] = (short)f2bf_rne(tile[o * 8 + e][n]);
        ((bf16x8*)out)[(size_t)(kt * 8 + o) * 4096 + nt * 64 + n] = v;
    }
}

// ---------------------------------------------------------------------------
// 128x128 bf16 GEMM, 16x16x32 MFMA, windowed register pipeline,
// 64 KiB LDS -> 2 BLOCKS PER CU (cross-block wave overlap fills the
// read/stage bubbles that kept all single-block variants at ~1150 TF).
// 256 thr = 4 waves (2M x 2N); per-wave 64x64 = acc[4][4] f32x4 (64 reg).
// BK=64 -> kk in {0,1}. LDS: buf(2) x [A 16KB | B 16KB] = 64 KiB.
// k-major LDS: region = 8 slabs (k-octets) x 128 rows x 16B; fragment
// ds_read_b128: 16-lane quarter reads 16 consecutive rows = 256 contiguous
// bytes -> conflict-free (r7/r9-verified, SQ_LDS_BANK_CONFLICT = 0).
//
// Per K-tile t (buf P, other Q), 2 windows (r6 schedule, 2 barriers/tile):
//   w0: [stage 8 -> Q(t+1)] [rd P kk1 -> O] SB [16 MFMA kk0 (E)] SB
//   w1: VMC(0) BAR [rd Q kk0 -> E] SB [16 MFMA kk1 (O)] SB BAR
// MFMA consumes only previous-window reads (compiler emits counted lgkm ->
// tail reads drain under MFMA). VMC(0) retires this tile's 8 stage loads;
// the ~600cyc stage->retire gap is hidden by the co-resident block (the
// mechanism: m97/m114 wave-level overlap -- requires the occupancy=2 this
// config restores). WAR: buf Q's last read (tile t-1 w0, kk1) is lgkm-forced
// before t-1 w1's MFMA, which precedes t-1's end-BAR, which precedes the
// stage into Q at t w0. RAW: VMC(0)+BAR before reads of the staged tile.
// ---------------------------------------------------------------------------
__global__ __launch_bounds__(256, 2) void gemm2b(const unsigned short* __restrict__ Ap,
                                                 const unsigned short* __restrict__ Bp,
                                                 float* __restrict__ C) {
    __shared__ unsigned short lds[32768];  // 64 KiB

    const int lane = threadIdx.x & 63;
    const int w    = threadIdx.x >> 6;   // 0..3
    const int wm   = w >> 1;             // 0..1
    const int wn   = w & 1;              // 0..1

    // bijective XCD swizzle (gridDim.x = 1024, 1024 % 8 == 0)
    const int nch = gridDim.x >> 3;
    const int swz = (blockIdx.x & 7) * nch + (blockIdx.x >> 3);
    const int bm  = swz >> 5;            // 0..31
    const int bn  = swz & 31;            // 0..31

    // ---- staging: wave w covers slabs {2w, 2w+1} x halves {0,1} for A and B ----
    // src (shorts): base + {0, 512, 32768, 33280}; advance 262144/tile.
    const unsigned short* gAt = Ap + 8 * ((size_t)bm * 128 + lane) + (size_t)w * 65536;
    const unsigned short* gBt = Bp + 8 * ((size_t)bn * 128 + lane) + (size_t)w * 65536;

    // dest (shorts): A region = buf*16384, slab 2w at w*2048; B region +8192.
#define STG(Q) do {                                                          \
        unsigned short* dA = lds + (Q) * 16384 + w * 2048;                   \
        unsigned short* dB = dA + 8192;                                      \
        gload_lds16(gAt,          dA);                                       \
        gload_lds16(gAt + 512,    dA + 512);                                 \
        gload_lds16(gAt + 32768,  dA + 1024);                                \
        gload_lds16(gAt + 33280,  dA + 1536);                                \
        gload_lds16(gBt,          dB);                                       \
        gload_lds16(gBt + 512,    dB + 512);                                 \
        gload_lds16(gBt + 32768,  dB + 1024);                                \
        gload_lds16(gBt + 33280,  dB + 1536);                                \
    } while (0)
#define ADV() do { gAt += 262144; gBt += 262144; } while (0)

    // ---- fragment reads (bytes): addr = P*32768 + [A:0|B:16384]
    //      + kk*8192 + hi*2048 + row*16 (+ frag*256) ----
    const int fr = lane & 15;
    const int hi = lane >> 4;
    const char* ldsc = (const char*)lds;
    const int adA = (wm * 64 + fr) * 16 + hi * 2048;
    const int adB = 16384 + (wn * 64 + fr) * 16 + hi * 2048;

#define RD_A(DST, P, KK) do { _Pragma("unroll")                              \
        for (int m_ = 0; m_ < 4; ++m_)                                       \
            DST[m_] = *(const bf16x8*)(ldsc + (P) * 32768 + (KK) * 8192 +    \
                                       adA + m_ * 256);                      \
    } while (0)
#define RD_B(DST, P, KK) do { _Pragma("unroll")                              \
        for (int n_ = 0; n_ < 4; ++n_)                                       \
            DST[n_] = *(const bf16x8*)(ldsc + (P) * 32768 + (KK) * 8192 +    \
                                       adB + n_ * 256);                      \
    } while (0)

#define MFMA16(AF, BF) do {                                                  \
        __builtin_amdgcn_s_setprio(1);                                       \
        _Pragma("unroll")                                                    \
        for (int m_ = 0; m_ < 4; ++m_)                                       \
            _Pragma("unroll")                                                \
            for (int n_ = 0; n_ < 4; ++n_)                                   \
                acc[m_][n_] = __builtin_amdgcn_mfma_f32_16x16x32_bf16(       \
                    AF[m_], BF[n_], acc[m_][n_], 0, 0, 0);                   \
        __builtin_amdgcn_s_setprio(0);                                       \
    } while (0)

// One K-tile: P = this tile's buf (literal), Q = other buf.
#define TILE(P, Q, DO_STG, DO_NXT, DO_SYNC) do {                             \
        if (DO_STG) STG(Q);                                                  \
        RD_A(aO, P, 1); RD_B(bO, P, 1); SB();                                \
        MFMA16(aE, bE); SB();                                                \
        if (DO_SYNC) { VMC(0); BAR(); }                                      \
        if (DO_NXT) { RD_A(aE, Q, 0); RD_B(bE, Q, 0); SB(); }                \
        MFMA16(aO, bO); SB();                                                \
        BAR();                                                               \
        if (DO_STG) ADV();                                                   \
    } while (0)

    f32x4 acc[4][4] = {};
    bf16x8 aE[4], aO[4], bE[4], bO[4];

    // ---- prologue: stage tile 0 -> buf0, retire, read kk0 -> E ----
    STG(0); ADV();
    VMC(0); BAR();
    RD_A(aE, 0, 0); RD_B(bE, 0, 0);

    // ---- tiles 0..61 (stage t+1 each), tile 62 (stages 63), tile 63 ----
    for (int i = 0; i < 31; ++i) {
        TILE(0, 1, 1, 1, 1);
        TILE(1, 0, 1, 1, 1);
    }
    TILE(0, 1, 1, 1, 1);   // tile 62
    TILE(1, 0, 0, 0, 0);   // tile 63

    // ---- C write: 16x16 layout col = lane&15, row = (lane>>4)*4 + reg ----
    const size_t crow = (size_t)(bm * 128 + wm * 64 + hi * 4);
    const int    ccol = bn * 128 + wn * 64 + fr;
#pragma unroll
    for (int mi = 0; mi < 4; ++mi)
#pragma unroll
        for (int ni = 0; ni < 4; ++ni) {
            const size_t row = crow + mi * 16;
            const int    col = ccol + ni * 16;
#pragma unroll
            for (int r = 0; r < 4; ++r)
                C[(row + r) * Ndim + col] = acc[mi][ni][r];
        }

#undef STG
#undef ADV
#undef RD_A
#undef RD_B
#undef MFMA16
#undef TILE
}

// ---------------------------------------------------------------------------
// Fallback if workspace too small: plain f32 tiles
// ---------------------------------------------------------------------------
__global__ void gemm_f32_naive(const float* __restrict__ A, const float* __restrict__ B,
                               float* __restrict__ C) {
    __shared__ float As[32][33], Bs[32][33];
    const int tx = threadIdx.x & 31, ty = threadIdx.x >> 5;
    const int row0 = blockIdx.y * 32, col0 = blockIdx.x * 32;
    float acc[4] = {0.f, 0.f, 0.f, 0.f};
    for (int k0 = 0; k0 < Kdim; k0 += 32) {
        for (int i = threadIdx.x; i < 32 * 32; i += 256) {
            int r = i >> 5, c = i & 31;
            As[r][c] = A[(size_t)(row0 + r) * Kdim + k0 + c];
            Bs[r][c] = B[(size_t)(k0 + r) * Ndim + col0 + c];
        }
        __syncthreads();
#pragma unroll 8
        for (int kk = 0; kk < 32; ++kk) {
            float bv = Bs[kk][tx];
#pragma unroll
            for (int i = 0; i < 4; ++i) acc[i] += As[ty + 8 * i][kk] * bv;
        }
        __syncthreads();
    }
#pragma unroll
    for (int i = 0; i < 4; ++i)
        C[(size_t)(row0 + ty + 8 * i) * Ndim + col0 + tx] = acc[i];
}

extern "C" void kernel_launch(void* const* d_in, const int* in_sizes, int n_in,
                              void* d_out, int out_size, void* d_ws, size_t ws_size,
                              hipStream_t stream) {
    const float* x = (const float*)d_in[0];
    const float* y = (const float*)d_in[1];
    float* out = (float*)d_out;

    const size_t elemsA = (size_t)Mdim * Kdim;
    const size_t elemsB = (size_t)Ndim * Kdim;
    const size_t need   = (elemsA + elemsB) * sizeof(unsigned short);  // 64 MiB

    if (ws_size >= need) {
        unsigned short* Apk = (unsigned short*)d_ws;
        unsigned short* Bpk = Apk + elemsA;

        conv_a_pack<<<dim3(Kdim / 64, Mdim / 64), 256, 0, stream>>>(x, Apk);
        conv_b_pack<<<dim3(Kdim / 64, Ndim / 64), 256, 0, stream>>>(y, Bpk);
        gemm2b<<<dim3((Mdim / 128) * (Ndim / 128)), 256, 0, stream>>>(Apk, Bpk, out);
    } else {
        gemm_f32_naive<<<dim3(Ndim / 32, Mdim / 32), 256, 0, stream>>>(x, y, out);
    }
}